// Round 9
// baseline (691.963 us; speedup 1.0000x reference)
//
#include <hip/hip_runtime.h>
#include <math.h>

// Problem constants
#define BB 2
#define RR 4096
#define NRAY (BB*RR)            // 8192
#define SC 48
#define NSAMP (NRAY*SC)         // 393216
#define CF 32
#define HID 64
#define ODIM 33                 // 1 sigma + 32 rgb
#define PRES 256
#define PLANE_HW (PRES*PRES)    // 65536
#define RAY_START 0.1f
#define RAY_END 2.0f
#define DELTA ((RAY_END-RAY_START)/(SC-1))

// workspace layout (in floats)
#define OFF_PLANES2  ((size_t)0)                        // 6*65536*64 bf16 = 12582912 floats
#define OFF_DEPTH_C  ((size_t)12582912)                 // 393216
#define OFF_SIGMA_C  (OFF_DEPTH_C + 393216)             // 393216
#define OFF_RGB_C    (OFF_SIGMA_C + 393216)             // 12582912
#define OFF_DEPTH_F  (OFF_RGB_C + 12582912)             // 393216
#define OFF_SIGMA_F  (OFF_DEPTH_F + 393216)             // 393216
#define OFF_RGB_F    (OFF_SIGMA_F + 393216)             // 12582912
#define OFF_MINMAX   (OFF_RGB_F + 12582912)             // 2 uints (+2 pad)
#define OFF_W2T      (OFF_MINMAX + 4)                   // 33*64 floats (w2 transposed)

typedef __attribute__((ext_vector_type(2))) float f2_t;

// packed fp32 FMA: acc.{x,y} += a.{x,y} * b.{x,y}  (one VOP3P inst = 2 FMA)
__device__ __forceinline__ void pk_fma_vv(f2_t& acc, f2_t a, f2_t b) {
    asm("v_pk_fma_f32 %0, %1, %2, %0" : "+v"(acc) : "v"(a), "v"(b));
}
// variant with the (single allowed) scalar operand: b must be wave-uniform
__device__ __forceinline__ void pk_fma_vs(f2_t& acc, f2_t a, f2_t b) {
    asm("v_pk_fma_f32 %0, %1, %2, %0" : "+v"(acc) : "v"(a), "s"(b));
}
// dword of 2 packed bf16 -> f2_t {lo, hi}
__device__ __forceinline__ f2_t bfpair(unsigned int u) {
    union { unsigned int i; float f; } lo, hi;
    lo.i = u << 16;
    hi.i = u & 0xffff0000u;
    f2_t r; r.x = lo.f; r.y = hi.f;
    return r;
}

__device__ __forceinline__ float softplusf(float x) {
    return fmaxf(x, 0.f) + __logf(1.f + __expf(-fabsf(x)));
}
__device__ __forceinline__ float sigact(float o) {
    float r = __builtin_amdgcn_rcpf(1.f + __expf(-o));
    return fmaf(1.002f, r, -0.001f);
}
__device__ __forceinline__ unsigned short f2bf(float f) {
    union { float f; unsigned int u; } v; v.f = f;
    unsigned int r = v.u + 0x7fffu + ((v.u >> 16) & 1u);   // RNE
    return (unsigned short)(r >> 16);
}
__device__ __forceinline__ unsigned int pack2(float lo, float hi) {
    return (unsigned int)f2bf(lo) | ((unsigned int)f2bf(hi) << 16);
}

// ---------------------------------------------------------------------------
// Kernel 1: precompute planes2[bp][y][x][j] = bf16( sum_c planes[bp][c][y][x] * w1[c][j] )
// Also: w2t[k][j] = w2[j][k].
__global__ __launch_bounds__(256) void precompute2(
    const float* __restrict__ planes, const float* __restrict__ w1,
    const float* __restrict__ w2,
    unsigned short* __restrict__ planes2, float* __restrict__ w2t)
{
    if (blockIdx.x == 0 && threadIdx.x < ODIM) {
        int k = threadIdx.x;
        for (int j = 0; j < HID; ++j) w2t[k * HID + j] = w2[j * ODIM + k];
    }
    int row = blockIdx.x;
    int bp = row >> 8, y = row & 255;
    int x = threadIdx.x;
    const float* src = planes + (size_t)bp * CF * PLANE_HW + (size_t)y * PRES + x;
    unsigned short* dst = planes2 + ((size_t)bp * PLANE_HW + (size_t)y * PRES + x) * HID;
    #pragma unroll
    for (int half = 0; half < 2; ++half) {
        f2_t acc[16];
        #pragma unroll
        for (int j = 0; j < 16; ++j) acc[j] = (f2_t){0.f, 0.f};
        for (int c = 0; c < CF; ++c) {
            float f = src[(size_t)c * PLANE_HW];
            f2_t fp; fp.x = f; fp.y = f;
            const f2_t* w1p = (const f2_t*)(w1 + c * HID + half * 32);
            #pragma unroll
            for (int j = 0; j < 16; ++j) pk_fma_vs(acc[j], fp, w1p[j]);
        }
        #pragma unroll
        for (int q = 0; q < 4; ++q) {
            uint4 u;
            u.x = pack2(acc[q*4+0].x, acc[q*4+0].y);
            u.y = pack2(acc[q*4+1].x, acc[q*4+1].y);
            u.z = pack2(acc[q*4+2].x, acc[q*4+2].y);
            u.w = pack2(acc[q*4+3].x, acc[q*4+3].y);
            ((uint4*)dst)[half*4 + q] = u;
        }
    }
}

// ---------------------------------------------------------------------------
// Kernel 2: gather + softplus + packed 64->33 GEMM2.
// R9: one sample per THREAD PAIR (R8 was latency-bound: VALU 30%, HBM 34%,
// occ 27%, 24-deep load chain/thread). Thread half=gid&1 owns 32 channels:
// 12-tap chain, pair covers the same 128B lines. Partial o[33] merged with
// one shfl_xor(1) per output. 2x waves for latency hiding.
__global__ __launch_bounds__(256, 3) void sample_mlp(
    const unsigned short* __restrict__ planes2,
    const float* __restrict__ depths_in,   // fine pass
    const float* __restrict__ noise,       // coarse pass
    float* __restrict__ depth_out,         // coarse pass
    const float* __restrict__ origins,
    const float* __restrict__ dirs,
    const float* __restrict__ b1,
    const float* __restrict__ w2t, const float* __restrict__ b2,
    float* __restrict__ sigma_out, float* __restrict__ rgb_out,
    int coarse)
{
    int tid = threadIdx.x;
    int gid2 = blockIdx.x * 256 + tid;
    int sample = gid2 >> 1;
    int half = gid2 & 1;
    int ray = sample / SC;
    int b = ray >> 12;

    float depth;
    if (coarse) {
        int s = sample - ray * SC;
        depth = RAY_START + (float)s * DELTA + noise[sample] * DELTA;
        if (half == 0) depth_out[sample] = depth;
    } else {
        depth = depths_in[sample];
    }

    float ox = origins[ray*3+0], oy = origins[ray*3+1], oz = origins[ray*3+2];
    float dx = dirs[ray*3+0],    dy = dirs[ray*3+1],    dz = dirs[ray*3+2];
    float cx = (ox + depth*dx) * 0.5f;
    float cy = (oy + depth*dy) * 0.5f;
    float cz = (oz + depth*dz) * 0.5f;

    f2_t h2[16];
    #pragma unroll
    for (int j = 0; j < 16; ++j) h2[j] = (f2_t){0.f, 0.f};

    #pragma unroll
    for (int p = 0; p < 3; ++p) {
        float gx = (p == 0) ? cx : (p == 1) ? cy : cz;
        float gy = (p == 0) ? cy : (p == 1) ? cz : cx;
        float x = fmaf(gx, 128.f, 127.5f);
        float y = fmaf(gy, 128.f, 127.5f);
        float x0f = floorf(x), y0f = floorf(y);
        float wx1 = x - x0f, wy1 = y - y0f;
        int x0 = (int)x0f, y0 = (int)y0f;
        const unsigned short* pb = planes2 + (size_t)(b*3 + p) * PLANE_HW * HID + half * 32;
        #pragma unroll
        for (int cyi = 0; cyi < 2; ++cyi) {
            #pragma unroll
            for (int cxi = 0; cxi < 2; ++cxi) {
                int xi = x0 + cxi, yi = y0 + cyi;
                float wgt = ((cyi ? wy1 : 1.f - wy1) * (cxi ? wx1 : 1.f - wx1)) * (1.f/3.f);
                if (xi < 0 || xi > 255 || yi < 0 || yi > 255) wgt = 0.f;
                int xc = min(max(xi, 0), 255), yc = min(max(yi, 0), 255);
                const uint4* tp = (const uint4*)(pb + (size_t)((yc << 8) + xc) * HID);
                uint4 v0 = tp[0], v1 = tp[1], v2 = tp[2], v3 = tp[3];
                f2_t wp2; wp2.x = wgt; wp2.y = wgt;
                pk_fma_vv(h2[0],  bfpair(v0.x), wp2);
                pk_fma_vv(h2[1],  bfpair(v0.y), wp2);
                pk_fma_vv(h2[2],  bfpair(v0.z), wp2);
                pk_fma_vv(h2[3],  bfpair(v0.w), wp2);
                pk_fma_vv(h2[4],  bfpair(v1.x), wp2);
                pk_fma_vv(h2[5],  bfpair(v1.y), wp2);
                pk_fma_vv(h2[6],  bfpair(v1.z), wp2);
                pk_fma_vv(h2[7],  bfpair(v1.w), wp2);
                pk_fma_vv(h2[8],  bfpair(v2.x), wp2);
                pk_fma_vv(h2[9],  bfpair(v2.y), wp2);
                pk_fma_vv(h2[10], bfpair(v2.z), wp2);
                pk_fma_vv(h2[11], bfpair(v2.w), wp2);
                pk_fma_vv(h2[12], bfpair(v3.x), wp2);
                pk_fma_vv(h2[13], bfpair(v3.y), wp2);
                pk_fma_vv(h2[14], bfpair(v3.z), wp2);
                pk_fma_vv(h2[15], bfpair(v3.w), wp2);
            }
        }
    }

    // bias + softplus for this thread's 32 channels
    #pragma unroll
    for (int j = 0; j < 16; ++j) {
        // half is not compile-time; b1 index is uniform within a wave? NO —
        // half alternates by lane. Load per-lane (VMEM, L1-hot, 2 dwords).
        h2[j].x = softplusf(h2[j].x + b1[half*32 + 2*j]);
        h2[j].y = softplusf(h2[j].y + b1[half*32 + 2*j + 1]);
    }

    // partial GEMM2 over own 32 channels; w2t row halves selected per-lane.
    float o[ODIM];
    const f2_t* wbase = (const f2_t*)(w2t + half * 32);
    #pragma unroll
    for (int k = 0; k < ODIM; ++k) {
        const f2_t* wp = wbase + k * (HID/2);
        f2_t acc = (f2_t){0.f, 0.f};
        #pragma unroll
        for (int j = 0; j < 16; ++j) pk_fma_vv(acc, h2[j], wp[j]);
        float part = acc.x + acc.y + (half ? 0.f : b2[k]);
        o[k] = part + __shfl_xor(part, 1);
    }

    if (half == 0) sigma_out[sample] = o[0];
    // pair-split rgb stores: thread half writes quarters [4h, 4h+4)
    float4* ro = (float4*)(rgb_out + (size_t)sample * 32);
    #pragma unroll
    for (int q = 0; q < 4; ++q) {
        int qq = half * 4 + q;
        float4 v;
        v.x = sigact(o[1 + qq*4 + 0]);
        v.y = sigact(o[1 + qq*4 + 1]);
        v.z = sigact(o[1 + qq*4 + 2]);
        v.w = sigact(o[1 + qq*4 + 3]);
        ro[qq] = v;
    }
}

// ---------------------------------------------------------------------------
// Kernel 3: importance sampling, one wave per ray; block-level minmax to
// scratch (bmin/bmax staged in rgb_f, overwritten later by the fine pass).
__global__ __launch_bounds__(256) void importance_kernel(
    const float* __restrict__ depth_c, const float* __restrict__ sigma_c,
    const float* __restrict__ noise_imp, float* __restrict__ depth_f,
    float* __restrict__ bmin, float* __restrict__ bmax)
{
    __shared__ float s_cdf[4][46];
    __shared__ float s_bins[4][47];
    __shared__ float s_red[8];
    int wave = threadIdx.x >> 6, lane = threadIdx.x & 63;
    int ray = blockIdx.x * 4 + wave;

    const float* d  = depth_c + (size_t)ray * SC;
    const float* sg = sigma_c + (size_t)ray * SC;
    float dval = (lane < SC) ? d[lane] : 0.f;
    float sval = (lane < SC) ? sg[lane] : 0.f;
    float dnext = __shfl_down(dval, 1);
    float snext = __shfl_down(sval, 1);

    float a = 0.f;
    if (lane < SC-1) {
        float dens = softplusf(0.5f * (sval + snext) - 1.f);
        a = 1.f - expf(-dens * (dnext - dval));
    }
    float f = (lane < SC-1) ? (1.f - a + 1e-10f) : 1.f;
    float incl = f;
    #pragma unroll
    for (int off = 1; off < 64; off <<= 1) {
        float t = __shfl_up(incl, off);
        if (lane >= off) incl *= t;
    }
    float T = (lane == 0) ? 1.f : __shfl_up(incl, 1);
    float w = a * T;
    float wm1 = __shfl_up(w, 1);
    float wp1 = __shfl_down(w, 1);
    float wn = 0.5f * (fmaxf(wm1, w) + fmaxf(w, wp1)) + 0.01f + 1e-5f;
    float g = (lane >= 1 && lane <= 45) ? wn : 0.f;
    float incl2 = g;
    #pragma unroll
    for (int off = 1; off < 64; off <<= 1) {
        float t = __shfl_up(incl2, off);
        if (lane >= off) incl2 += t;
    }
    float sum = __shfl(incl2, 45);
    if (lane == 0) s_cdf[wave][0] = 0.f;
    else if (lane <= 45) s_cdf[wave][lane] = incl2 / sum;
    if (lane < SC-1) s_bins[wave][lane] = 0.5f * (dval + dnext);
    __syncthreads();

    float fmn = 1e30f, fmx = -1e30f;
    if (lane < SC) {
        float u = noise_imp[(size_t)ray * SC + lane];
        int inds = 0;
        #pragma unroll
        for (int t = 0; t < 46; ++t) inds += (s_cdf[wave][t] <= u) ? 1 : 0;
        int below = max(inds - 1, 0), above = min(inds, 45);
        float cb = s_cdf[wave][below], ca = s_cdf[wave][above];
        float bb = s_bins[wave][below], ba = s_bins[wave][above];
        float den = (ca - cb < 1e-5f) ? 1.f : (ca - cb);
        float s = bb + (u - cb) / den * (ba - bb);
        depth_f[(size_t)ray * SC + lane] = s;
        fmn = s; fmx = s;
    }
    float d0 = __shfl(dval, 0), dlast = __shfl(dval, SC-1);
    fmn = fminf(fmn, d0); fmx = fmaxf(fmx, dlast);
    #pragma unroll
    for (int off = 32; off >= 1; off >>= 1) {
        fmn = fminf(fmn, __shfl_xor(fmn, off));
        fmx = fmaxf(fmx, __shfl_xor(fmx, off));
    }
    if (lane == 0) { s_red[wave] = fmn; s_red[4 + wave] = fmx; }
    __syncthreads();
    if (threadIdx.x == 0) {
        bmin[blockIdx.x] = fminf(fminf(s_red[0], s_red[1]), fminf(s_red[2], s_red[3]));
        bmax[blockIdx.x] = fmaxf(fmaxf(s_red[4], s_red[5]), fmaxf(s_red[6], s_red[7]));
    }
}

// ---------------------------------------------------------------------------
// Kernel 3b: fold 2048 per-block (min,max) pairs into minmax[0..1]. 1 block.
__global__ __launch_bounds__(1024) void reduce_minmax(
    const float* __restrict__ bmin, const float* __restrict__ bmax,
    unsigned int* __restrict__ minmax)
{
    int tid = threadIdx.x;
    float mn = fminf(bmin[tid], bmin[tid + 1024]);
    float mx = fmaxf(bmax[tid], bmax[tid + 1024]);
    #pragma unroll
    for (int off = 32; off >= 1; off >>= 1) {
        mn = fminf(mn, __shfl_xor(mn, off));
        mx = fmaxf(mx, __shfl_xor(mx, off));
    }
    __shared__ float smn[16], smx[16];
    int wv = tid >> 6;
    if ((tid & 63) == 0) { smn[wv] = mn; smx[wv] = mx; }
    __syncthreads();
    if (tid == 0) {
        float m = smn[0], M = smx[0];
        #pragma unroll
        for (int i = 1; i < 16; ++i) { m = fminf(m, smn[i]); M = fmaxf(M, smx[i]); }
        minmax[0] = __float_as_uint(m);
        minmax[1] = __float_as_uint(M);
    }
}

// ---------------------------------------------------------------------------
// Kernel 4: merge coarse+fine (stable rank sort of 96), final ray-march.
__global__ __launch_bounds__(256) void final_march(
    const float* __restrict__ depth_c, const float* __restrict__ sigma_c,
    const float* __restrict__ rgb_c,
    const float* __restrict__ depth_f, const float* __restrict__ sigma_f,
    const float* __restrict__ rgb_f,
    const unsigned int* __restrict__ minmax,
    float* __restrict__ out)
{
    __shared__ float dall[4][96];
    __shared__ float sall[4][96];
    __shared__ float dsrt[4][96];
    __shared__ float ssrt[4][96];
    __shared__ int   perm[4][96];
    __shared__ float al[4][96];

    int wid = threadIdx.x >> 6, lane = threadIdx.x & 63;
    int ray = blockIdx.x * 4 + wid;

    for (int j = lane; j < 96; j += 64) {
        float dv, sv;
        if (j < 48) { dv = depth_c[(size_t)ray*48 + j]; sv = sigma_c[(size_t)ray*48 + j]; }
        else        { dv = depth_f[(size_t)ray*48 + j-48]; sv = sigma_f[(size_t)ray*48 + j-48]; }
        dall[wid][j] = dv; sall[wid][j] = sv;
    }
    __syncthreads();
    for (int j = lane; j < 96; j += 64) {
        float dj = dall[wid][j];
        int rank = 0;
        for (int k = 0; k < 96; ++k) {
            float dk = dall[wid][k];
            rank += (dk < dj || (dk == dj && k < j)) ? 1 : 0;
        }
        dsrt[wid][rank] = dj;
        ssrt[wid][rank] = sall[wid][j];
        perm[wid][rank] = j;
    }
    __syncthreads();
    for (int i = lane; i < 95; i += 64) {
        float dlt = dsrt[wid][i+1] - dsrt[wid][i];
        float dens = softplusf(0.5f * (ssrt[wid][i] + ssrt[wid][i+1]) - 1.f);
        al[wid][i] = 1.f - expf(-dens * dlt);
    }
    __syncthreads();
    if (lane == 0) {
        float T = 1.f, wsum = 0.f, dsum = 0.f;
        for (int i = 0; i < 95; ++i) {
            float a = al[wid][i];
            float wloc = a * T;
            T *= 1.f - a + 1e-10f;
            al[wid][i] = wloc;
            wsum += wloc;
            dsum += wloc * 0.5f * (dsrt[wid][i] + dsrt[wid][i+1]);
        }
        float depth = dsum / wsum;
        if (isnan(depth)) depth = INFINITY;
        float gmn = __uint_as_float(minmax[0]);
        float gmx = __uint_as_float(minmax[1]);
        depth = fminf(fmaxf(depth, gmn), gmx);
        out[262144 + ray] = depth;
        out[270336 + ray] = wsum;
        out[278528 + ray] = T;
    }
    __syncthreads();
    int k = lane & 31, half = lane >> 5;
    int i0 = half * 48, i1 = half ? 95 : 48;
    const float* rc = rgb_c + (size_t)ray * 48 * 32;
    const float* rf = rgb_f + (size_t)ray * 48 * 32;
    float acc = 0.f;
    int j0 = perm[wid][i0];
    float cur = (j0 < 48) ? rc[j0*32 + k] : rf[(j0-48)*32 + k];
    for (int i = i0; i < i1; ++i) {
        int jn = perm[wid][i+1];
        float nxt = (jn < 48) ? rc[jn*32 + k] : rf[(jn-48)*32 + k];
        acc += al[wid][i] * (cur + nxt);
        cur = nxt;
    }
    acc *= 0.5f;
    acc += __shfl_xor(acc, 32);
    if (half == 0) out[(size_t)ray * 32 + k] = acc * 2.f - 1.f;
}

// ---------------------------------------------------------------------------
extern "C" void kernel_launch(void* const* d_in, const int* in_sizes, int n_in,
                              void* d_out, int out_size, void* d_ws, size_t ws_size,
                              hipStream_t stream) {
    const float* planes      = (const float*)d_in[0];
    const float* origins     = (const float*)d_in[1];
    const float* dirs        = (const float*)d_in[2];
    const float* w1          = (const float*)d_in[3];
    const float* b1          = (const float*)d_in[4];
    const float* w2          = (const float*)d_in[5];
    const float* b2          = (const float*)d_in[6];
    const float* noise_strat = (const float*)d_in[7];
    const float* noise_imp   = (const float*)d_in[8];
    float* out = (float*)d_out;
    float* ws  = (float*)d_ws;

    unsigned short* planes2 = (unsigned short*)(ws + OFF_PLANES2);
    float* depth_c = ws + OFF_DEPTH_C;
    float* sigma_c = ws + OFF_SIGMA_C;
    float* rgb_c   = ws + OFF_RGB_C;
    float* depth_f = ws + OFF_DEPTH_F;
    float* sigma_f = ws + OFF_SIGMA_F;
    float* rgb_f   = ws + OFF_RGB_F;
    unsigned int* minmax = (unsigned int*)(ws + OFF_MINMAX);
    float* w2t = ws + OFF_W2T;
    // per-block minmax scratch: staged in rgb_f (overwritten later by fine pass)
    float* bmin = rgb_f;
    float* bmax = rgb_f + 2048;

    precompute2<<<1536, 256, 0, stream>>>(planes, w1, w2, planes2, w2t);
    sample_mlp<<<NSAMP*2/256, 256, 0, stream>>>(planes2, nullptr, noise_strat, depth_c,
                                                origins, dirs, b1, w2t, b2,
                                                sigma_c, rgb_c, 1);
    importance_kernel<<<NRAY/4, 256, 0, stream>>>(depth_c, sigma_c, noise_imp,
                                                  depth_f, bmin, bmax);
    reduce_minmax<<<1, 1024, 0, stream>>>(bmin, bmax, minmax);
    sample_mlp<<<NSAMP*2/256, 256, 0, stream>>>(planes2, depth_f, nullptr, nullptr,
                                                origins, dirs, b1, w2t, b2,
                                                sigma_f, rgb_f, 0);
    final_march<<<NRAY/4, 256, 0, stream>>>(depth_c, sigma_c, rgb_c,
                                            depth_f, sigma_f, rgb_f, minmax, out);
}

// Round 10
// 435.518 us; speedup vs baseline: 1.5888x; 1.5888x over previous
//
#include <hip/hip_runtime.h>
#include <math.h>

// Problem constants
#define BB 2
#define RR 4096
#define NRAY (BB*RR)            // 8192
#define SC 48
#define NSAMP (NRAY*SC)         // 393216
#define CF 32
#define HID 64
#define ODIM 33                 // 1 sigma + 32 rgb
#define PRES 256
#define PLANE_HW (PRES*PRES)    // 65536
#define RAY_START 0.1f
#define RAY_END 2.0f
#define DELTA ((RAY_END-RAY_START)/(SC-1))

// workspace layout (in floats)
#define OFF_PLANES2  ((size_t)0)                        // 6*65536*64 bf16 = 12582912 floats
#define OFF_DEPTH_C  ((size_t)12582912)                 // 393216
#define OFF_SIGMA_C  (OFF_DEPTH_C + 393216)             // 393216
#define OFF_RGB_C    (OFF_SIGMA_C + 393216)             // 12582912
#define OFF_DEPTH_F  (OFF_RGB_C + 12582912)             // 393216
#define OFF_SIGMA_F  (OFF_DEPTH_F + 393216)             // 393216
#define OFF_RGB_F    (OFF_SIGMA_F + 393216)             // 12582912
#define OFF_MINMAX   (OFF_RGB_F + 12582912)             // 2 uints (+2 pad)
#define OFF_W2T      (OFF_MINMAX + 4)                   // 33*64 floats (w2 transposed)

typedef __attribute__((ext_vector_type(2))) float f2_t;

// packed fp32 FMA: acc.{x,y} += a.{x,y} * b.{x,y}  (one VOP3P inst = 2 FMA)
__device__ __forceinline__ void pk_fma_vv(f2_t& acc, f2_t a, f2_t b) {
    asm("v_pk_fma_f32 %0, %1, %2, %0" : "+v"(acc) : "v"(a), "v"(b));
}
// variant with the (single allowed) scalar operand: b must be wave-uniform
__device__ __forceinline__ void pk_fma_vs(f2_t& acc, f2_t a, f2_t b) {
    asm("v_pk_fma_f32 %0, %1, %2, %0" : "+v"(acc) : "v"(a), "s"(b));
}
// dword of 2 packed bf16 -> f2_t {lo, hi}
__device__ __forceinline__ f2_t bfpair(unsigned int u) {
    union { unsigned int i; float f; } lo, hi;
    lo.i = u << 16;
    hi.i = u & 0xffff0000u;
    f2_t r; r.x = lo.f; r.y = hi.f;
    return r;
}

__device__ __forceinline__ float softplusf(float x) {
    return fmaxf(x, 0.f) + __logf(1.f + __expf(-fabsf(x)));
}
__device__ __forceinline__ float sigact(float o) {
    float r = __builtin_amdgcn_rcpf(1.f + __expf(-o));
    return fmaf(1.002f, r, -0.001f);
}
__device__ __forceinline__ unsigned short f2bf(float f) {
    union { float f; unsigned int u; } v; v.f = f;
    unsigned int r = v.u + 0x7fffu + ((v.u >> 16) & 1u);   // RNE
    return (unsigned short)(r >> 16);
}
__device__ __forceinline__ unsigned int pack2(float lo, float hi) {
    return (unsigned int)f2bf(lo) | ((unsigned int)f2bf(hi) << 16);
}

// ---------------------------------------------------------------------------
// Kernel 1: precompute planes2[bp][y][x][j] = bf16( sum_c planes[bp][c][y][x] * w1[c][j] )
// Also: w2t[k][j] = w2[j][k].
__global__ __launch_bounds__(256) void precompute2(
    const float* __restrict__ planes, const float* __restrict__ w1,
    const float* __restrict__ w2,
    unsigned short* __restrict__ planes2, float* __restrict__ w2t)
{
    if (blockIdx.x == 0 && threadIdx.x < ODIM) {
        int k = threadIdx.x;
        for (int j = 0; j < HID; ++j) w2t[k * HID + j] = w2[j * ODIM + k];
    }
    int row = blockIdx.x;
    int bp = row >> 8, y = row & 255;
    int x = threadIdx.x;
    const float* src = planes + (size_t)bp * CF * PLANE_HW + (size_t)y * PRES + x;
    unsigned short* dst = planes2 + ((size_t)bp * PLANE_HW + (size_t)y * PRES + x) * HID;
    #pragma unroll
    for (int half = 0; half < 2; ++half) {
        f2_t acc[16];
        #pragma unroll
        for (int j = 0; j < 16; ++j) acc[j] = (f2_t){0.f, 0.f};
        for (int c = 0; c < CF; ++c) {
            float f = src[(size_t)c * PLANE_HW];
            f2_t fp; fp.x = f; fp.y = f;
            const f2_t* w1p = (const f2_t*)(w1 + c * HID + half * 32);
            #pragma unroll
            for (int j = 0; j < 16; ++j) pk_fma_vs(acc[j], fp, w1p[j]);
        }
        #pragma unroll
        for (int q = 0; q < 4; ++q) {
            uint4 u;
            u.x = pack2(acc[q*4+0].x, acc[q*4+0].y);
            u.y = pack2(acc[q*4+1].x, acc[q*4+1].y);
            u.z = pack2(acc[q*4+2].x, acc[q*4+2].y);
            u.w = pack2(acc[q*4+3].x, acc[q*4+3].y);
            ((uint4*)dst)[half*4 + q] = u;
        }
    }
}

// ---------------------------------------------------------------------------
// Kernel 2: gather + softplus + packed 64->33 GEMM2.
// R10: sample split across a WAVE PAIR (R9's lane-parity split scalarized the
// weight loads -> TA-bound; SGPR 112->32 was the tell). half = wave&1 via
// readfirstlane stays in an SGPR, so w2t/b1 loads remain scalar. Odd wave
// writes partial o[33] to LDS; even wave merges + does the R8-style fully
// coalesced 128B/sample stores. 12-tap chain/thread, 2x waves vs R8.
__global__ __launch_bounds__(256, 3) void sample_mlp(
    const unsigned short* __restrict__ planes2,
    const float* __restrict__ depths_in,   // fine pass
    const float* __restrict__ noise,       // coarse pass
    float* __restrict__ depth_out,         // coarse pass
    const float* __restrict__ origins,
    const float* __restrict__ dirs,
    const float* __restrict__ b1,
    const float* __restrict__ w2t, const float* __restrict__ b2,
    float* __restrict__ sigma_out, float* __restrict__ rgb_out,
    int coarse)
{
    __shared__ __align__(8) float s_part[2][64][34];   // 17408 B, stride-34 rows

    int lane = threadIdx.x & 63;
    int wv = threadIdx.x >> 6;
    int halfu = __builtin_amdgcn_readfirstlane(wv & 1);   // SGPR: keeps weight loads scalar
    int pairu = __builtin_amdgcn_readfirstlane(wv >> 1);
    int sample = blockIdx.x * 128 + pairu * 64 + lane;
    int ray = sample / SC;
    int b = ray >> 12;

    float depth;
    if (coarse) {
        int s = sample - ray * SC;
        depth = RAY_START + (float)s * DELTA + noise[sample] * DELTA;
        if (halfu == 0) depth_out[sample] = depth;
    } else {
        depth = depths_in[sample];
    }

    float ox = origins[ray*3+0], oy = origins[ray*3+1], oz = origins[ray*3+2];
    float dx = dirs[ray*3+0],    dy = dirs[ray*3+1],    dz = dirs[ray*3+2];
    float cx = (ox + depth*dx) * 0.5f;
    float cy = (oy + depth*dy) * 0.5f;
    float cz = (oz + depth*dz) * 0.5f;

    f2_t h2[16];
    #pragma unroll
    for (int j = 0; j < 16; ++j) h2[j] = (f2_t){0.f, 0.f};

    #pragma unroll
    for (int p = 0; p < 3; ++p) {
        float gx = (p == 0) ? cx : (p == 1) ? cy : cz;
        float gy = (p == 0) ? cy : (p == 1) ? cz : cx;
        float x = fmaf(gx, 128.f, 127.5f);
        float y = fmaf(gy, 128.f, 127.5f);
        float x0f = floorf(x), y0f = floorf(y);
        float wx1 = x - x0f, wy1 = y - y0f;
        int x0 = (int)x0f, y0 = (int)y0f;
        const unsigned short* pb = planes2 + (size_t)(b*3 + p) * PLANE_HW * HID + halfu * 32;
        #pragma unroll
        for (int cyi = 0; cyi < 2; ++cyi) {
            #pragma unroll
            for (int cxi = 0; cxi < 2; ++cxi) {
                int xi = x0 + cxi, yi = y0 + cyi;
                float wgt = ((cyi ? wy1 : 1.f - wy1) * (cxi ? wx1 : 1.f - wx1)) * (1.f/3.f);
                if (xi < 0 || xi > 255 || yi < 0 || yi > 255) wgt = 0.f;
                int xc = min(max(xi, 0), 255), yc = min(max(yi, 0), 255);
                const uint4* tp = (const uint4*)(pb + (size_t)((yc << 8) + xc) * HID);
                uint4 v0 = tp[0], v1 = tp[1], v2 = tp[2], v3 = tp[3];
                f2_t wp2; wp2.x = wgt; wp2.y = wgt;
                pk_fma_vv(h2[0],  bfpair(v0.x), wp2);
                pk_fma_vv(h2[1],  bfpair(v0.y), wp2);
                pk_fma_vv(h2[2],  bfpair(v0.z), wp2);
                pk_fma_vv(h2[3],  bfpair(v0.w), wp2);
                pk_fma_vv(h2[4],  bfpair(v1.x), wp2);
                pk_fma_vv(h2[5],  bfpair(v1.y), wp2);
                pk_fma_vv(h2[6],  bfpair(v1.z), wp2);
                pk_fma_vv(h2[7],  bfpair(v1.w), wp2);
                pk_fma_vv(h2[8],  bfpair(v2.x), wp2);
                pk_fma_vv(h2[9],  bfpair(v2.y), wp2);
                pk_fma_vv(h2[10], bfpair(v2.z), wp2);
                pk_fma_vv(h2[11], bfpair(v2.w), wp2);
                pk_fma_vv(h2[12], bfpair(v3.x), wp2);
                pk_fma_vv(h2[13], bfpair(v3.y), wp2);
                pk_fma_vv(h2[14], bfpair(v3.z), wp2);
                pk_fma_vv(h2[15], bfpair(v3.w), wp2);
            }
        }
    }

    // bias + softplus for this wave's 32 channels (halfu is SGPR -> scalar b1)
    #pragma unroll
    for (int j = 0; j < 16; ++j) {
        h2[j].x = softplusf(h2[j].x + b1[halfu*32 + 2*j]);
        h2[j].y = softplusf(h2[j].y + b1[halfu*32 + 2*j + 1]);
    }

    // partial GEMM2 over own 32 channels; w2t row halves via SGPR offset.
    float o[ODIM + 1];   // pad to 34 for f2 LDS traffic
    const f2_t* wbase = (const f2_t*)(w2t + halfu * 32);
    #pragma unroll
    for (int k = 0; k < ODIM; ++k) {
        const f2_t* wp = wbase + k * (HID/2);
        f2_t acc = (f2_t){0.f, 0.f};
        #pragma unroll
        for (int j = 0; j < 16; ++j) pk_fma_vs(acc, h2[j], wp[j]);
        o[k] = acc.x + acc.y;
    }
    o[ODIM] = 0.f;

    if (halfu) {
        f2_t* dstp = (f2_t*)&s_part[pairu][lane][0];
        #pragma unroll
        for (int j = 0; j < 17; ++j) {
            f2_t v; v.x = o[2*j]; v.y = o[2*j+1];
            dstp[j] = v;
        }
    }
    __syncthreads();
    if (!halfu) {
        const f2_t* srcp = (const f2_t*)&s_part[pairu][lane][0];
        #pragma unroll
        for (int j = 0; j < 17; ++j) {
            f2_t v = srcp[j];
            o[2*j]   += v.x;
            o[2*j+1] += v.y;
        }
        #pragma unroll
        for (int k = 0; k < ODIM; ++k) o[k] += b2[k];

        sigma_out[sample] = o[0];
        float4* ro = (float4*)(rgb_out + (size_t)sample * 32);
        #pragma unroll
        for (int q = 0; q < 8; ++q) {
            float4 v;
            v.x = sigact(o[1 + q*4 + 0]);
            v.y = sigact(o[1 + q*4 + 1]);
            v.z = sigact(o[1 + q*4 + 2]);
            v.w = sigact(o[1 + q*4 + 3]);
            ro[q] = v;
        }
    }
}

// ---------------------------------------------------------------------------
// Kernel 3: importance sampling, one wave per ray; block-level minmax to
// scratch (bmin/bmax staged in rgb_f, overwritten later by the fine pass).
__global__ __launch_bounds__(256) void importance_kernel(
    const float* __restrict__ depth_c, const float* __restrict__ sigma_c,
    const float* __restrict__ noise_imp, float* __restrict__ depth_f,
    float* __restrict__ bmin, float* __restrict__ bmax)
{
    __shared__ float s_cdf[4][46];
    __shared__ float s_bins[4][47];
    __shared__ float s_red[8];
    int wave = threadIdx.x >> 6, lane = threadIdx.x & 63;
    int ray = blockIdx.x * 4 + wave;

    const float* d  = depth_c + (size_t)ray * SC;
    const float* sg = sigma_c + (size_t)ray * SC;
    float dval = (lane < SC) ? d[lane] : 0.f;
    float sval = (lane < SC) ? sg[lane] : 0.f;
    float dnext = __shfl_down(dval, 1);
    float snext = __shfl_down(sval, 1);

    float a = 0.f;
    if (lane < SC-1) {
        float dens = softplusf(0.5f * (sval + snext) - 1.f);
        a = 1.f - expf(-dens * (dnext - dval));
    }
    float f = (lane < SC-1) ? (1.f - a + 1e-10f) : 1.f;
    float incl = f;
    #pragma unroll
    for (int off = 1; off < 64; off <<= 1) {
        float t = __shfl_up(incl, off);
        if (lane >= off) incl *= t;
    }
    float T = (lane == 0) ? 1.f : __shfl_up(incl, 1);
    float w = a * T;
    float wm1 = __shfl_up(w, 1);
    float wp1 = __shfl_down(w, 1);
    float wn = 0.5f * (fmaxf(wm1, w) + fmaxf(w, wp1)) + 0.01f + 1e-5f;
    float g = (lane >= 1 && lane <= 45) ? wn : 0.f;
    float incl2 = g;
    #pragma unroll
    for (int off = 1; off < 64; off <<= 1) {
        float t = __shfl_up(incl2, off);
        if (lane >= off) incl2 += t;
    }
    float sum = __shfl(incl2, 45);
    if (lane == 0) s_cdf[wave][0] = 0.f;
    else if (lane <= 45) s_cdf[wave][lane] = incl2 / sum;
    if (lane < SC-1) s_bins[wave][lane] = 0.5f * (dval + dnext);
    __syncthreads();

    float fmn = 1e30f, fmx = -1e30f;
    if (lane < SC) {
        float u = noise_imp[(size_t)ray * SC + lane];
        int inds = 0;
        #pragma unroll
        for (int t = 0; t < 46; ++t) inds += (s_cdf[wave][t] <= u) ? 1 : 0;
        int below = max(inds - 1, 0), above = min(inds, 45);
        float cb = s_cdf[wave][below], ca = s_cdf[wave][above];
        float bb = s_bins[wave][below], ba = s_bins[wave][above];
        float den = (ca - cb < 1e-5f) ? 1.f : (ca - cb);
        float s = bb + (u - cb) / den * (ba - bb);
        depth_f[(size_t)ray * SC + lane] = s;
        fmn = s; fmx = s;
    }
    float d0 = __shfl(dval, 0), dlast = __shfl(dval, SC-1);
    fmn = fminf(fmn, d0); fmx = fmaxf(fmx, dlast);
    #pragma unroll
    for (int off = 32; off >= 1; off >>= 1) {
        fmn = fminf(fmn, __shfl_xor(fmn, off));
        fmx = fmaxf(fmx, __shfl_xor(fmx, off));
    }
    if (lane == 0) { s_red[wave] = fmn; s_red[4 + wave] = fmx; }
    __syncthreads();
    if (threadIdx.x == 0) {
        bmin[blockIdx.x] = fminf(fminf(s_red[0], s_red[1]), fminf(s_red[2], s_red[3]));
        bmax[blockIdx.x] = fmaxf(fmaxf(s_red[4], s_red[5]), fmaxf(s_red[6], s_red[7]));
    }
}

// ---------------------------------------------------------------------------
// Kernel 3b: fold 2048 per-block (min,max) pairs into minmax[0..1]. 1 block.
__global__ __launch_bounds__(1024) void reduce_minmax(
    const float* __restrict__ bmin, const float* __restrict__ bmax,
    unsigned int* __restrict__ minmax)
{
    int tid = threadIdx.x;
    float mn = fminf(bmin[tid], bmin[tid + 1024]);
    float mx = fmaxf(bmax[tid], bmax[tid + 1024]);
    #pragma unroll
    for (int off = 32; off >= 1; off >>= 1) {
        mn = fminf(mn, __shfl_xor(mn, off));
        mx = fmaxf(mx, __shfl_xor(mx, off));
    }
    __shared__ float smn[16], smx[16];
    int wv = tid >> 6;
    if ((tid & 63) == 0) { smn[wv] = mn; smx[wv] = mx; }
    __syncthreads();
    if (tid == 0) {
        float m = smn[0], M = smx[0];
        #pragma unroll
        for (int i = 1; i < 16; ++i) { m = fminf(m, smn[i]); M = fmaxf(M, smx[i]); }
        minmax[0] = __float_as_uint(m);
        minmax[1] = __float_as_uint(M);
    }
}

// ---------------------------------------------------------------------------
// Kernel 4: merge coarse+fine (stable rank sort of 96), final ray-march.
__global__ __launch_bounds__(256) void final_march(
    const float* __restrict__ depth_c, const float* __restrict__ sigma_c,
    const float* __restrict__ rgb_c,
    const float* __restrict__ depth_f, const float* __restrict__ sigma_f,
    const float* __restrict__ rgb_f,
    const unsigned int* __restrict__ minmax,
    float* __restrict__ out)
{
    __shared__ float dall[4][96];
    __shared__ float sall[4][96];
    __shared__ float dsrt[4][96];
    __shared__ float ssrt[4][96];
    __shared__ int   perm[4][96];
    __shared__ float al[4][96];

    int wid = threadIdx.x >> 6, lane = threadIdx.x & 63;
    int ray = blockIdx.x * 4 + wid;

    for (int j = lane; j < 96; j += 64) {
        float dv, sv;
        if (j < 48) { dv = depth_c[(size_t)ray*48 + j]; sv = sigma_c[(size_t)ray*48 + j]; }
        else        { dv = depth_f[(size_t)ray*48 + j-48]; sv = sigma_f[(size_t)ray*48 + j-48]; }
        dall[wid][j] = dv; sall[wid][j] = sv;
    }
    __syncthreads();
    for (int j = lane; j < 96; j += 64) {
        float dj = dall[wid][j];
        int rank = 0;
        for (int k = 0; k < 96; ++k) {
            float dk = dall[wid][k];
            rank += (dk < dj || (dk == dj && k < j)) ? 1 : 0;
        }
        dsrt[wid][rank] = dj;
        ssrt[wid][rank] = sall[wid][j];
        perm[wid][rank] = j;
    }
    __syncthreads();
    for (int i = lane; i < 95; i += 64) {
        float dlt = dsrt[wid][i+1] - dsrt[wid][i];
        float dens = softplusf(0.5f * (ssrt[wid][i] + ssrt[wid][i+1]) - 1.f);
        al[wid][i] = 1.f - expf(-dens * dlt);
    }
    __syncthreads();
    if (lane == 0) {
        float T = 1.f, wsum = 0.f, dsum = 0.f;
        for (int i = 0; i < 95; ++i) {
            float a = al[wid][i];
            float wloc = a * T;
            T *= 1.f - a + 1e-10f;
            al[wid][i] = wloc;
            wsum += wloc;
            dsum += wloc * 0.5f * (dsrt[wid][i] + dsrt[wid][i+1]);
        }
        float depth = dsum / wsum;
        if (isnan(depth)) depth = INFINITY;
        float gmn = __uint_as_float(minmax[0]);
        float gmx = __uint_as_float(minmax[1]);
        depth = fminf(fmaxf(depth, gmn), gmx);
        out[262144 + ray] = depth;
        out[270336 + ray] = wsum;
        out[278528 + ray] = T;
    }
    __syncthreads();
    int k = lane & 31, half = lane >> 5;
    int i0 = half * 48, i1 = half ? 95 : 48;
    const float* rc = rgb_c + (size_t)ray * 48 * 32;
    const float* rf = rgb_f + (size_t)ray * 48 * 32;
    float acc = 0.f;
    int j0 = perm[wid][i0];
    float cur = (j0 < 48) ? rc[j0*32 + k] : rf[(j0-48)*32 + k];
    for (int i = i0; i < i1; ++i) {
        int jn = perm[wid][i+1];
        float nxt = (jn < 48) ? rc[jn*32 + k] : rf[(jn-48)*32 + k];
        acc += al[wid][i] * (cur + nxt);
        cur = nxt;
    }
    acc *= 0.5f;
    acc += __shfl_xor(acc, 32);
    if (half == 0) out[(size_t)ray * 32 + k] = acc * 2.f - 1.f;
}

// ---------------------------------------------------------------------------
extern "C" void kernel_launch(void* const* d_in, const int* in_sizes, int n_in,
                              void* d_out, int out_size, void* d_ws, size_t ws_size,
                              hipStream_t stream) {
    const float* planes      = (const float*)d_in[0];
    const float* origins     = (const float*)d_in[1];
    const float* dirs        = (const float*)d_in[2];
    const float* w1          = (const float*)d_in[3];
    const float* b1          = (const float*)d_in[4];
    const float* w2          = (const float*)d_in[5];
    const float* b2          = (const float*)d_in[6];
    const float* noise_strat = (const float*)d_in[7];
    const float* noise_imp   = (const float*)d_in[8];
    float* out = (float*)d_out;
    float* ws  = (float*)d_ws;

    unsigned short* planes2 = (unsigned short*)(ws + OFF_PLANES2);
    float* depth_c = ws + OFF_DEPTH_C;
    float* sigma_c = ws + OFF_SIGMA_C;
    float* rgb_c   = ws + OFF_RGB_C;
    float* depth_f = ws + OFF_DEPTH_F;
    float* sigma_f = ws + OFF_SIGMA_F;
    float* rgb_f   = ws + OFF_RGB_F;
    unsigned int* minmax = (unsigned int*)(ws + OFF_MINMAX);
    float* w2t = ws + OFF_W2T;
    // per-block minmax scratch: staged in rgb_f (overwritten later by fine pass)
    float* bmin = rgb_f;
    float* bmax = rgb_f + 2048;

    precompute2<<<1536, 256, 0, stream>>>(planes, w1, w2, planes2, w2t);
    sample_mlp<<<NSAMP/128, 256, 0, stream>>>(planes2, nullptr, noise_strat, depth_c,
                                              origins, dirs, b1, w2t, b2,
                                              sigma_c, rgb_c, 1);
    importance_kernel<<<NRAY/4, 256, 0, stream>>>(depth_c, sigma_c, noise_imp,
                                                  depth_f, bmin, bmax);
    reduce_minmax<<<1, 1024, 0, stream>>>(bmin, bmax, minmax);
    sample_mlp<<<NSAMP/128, 256, 0, stream>>>(planes2, depth_f, nullptr, nullptr,
                                              origins, dirs, b1, w2t, b2,
                                              sigma_f, rgb_f, 0);
    final_march<<<NRAY/4, 256, 0, stream>>>(depth_c, sigma_c, rgb_c,
                                            depth_f, sigma_f, rgb_f, minmax, out);
}

// Round 12
// 419.862 us; speedup vs baseline: 1.6481x; 1.0373x over previous
//
#include <hip/hip_runtime.h>
#include <math.h>

// Problem constants
#define BB 2
#define RR 4096
#define NRAY (BB*RR)            // 8192
#define SC 48
#define NSAMP (NRAY*SC)         // 393216
#define CF 32
#define HID 64
#define ODIM 33                 // 1 sigma + 32 rgb
#define PRES 256
#define PLANE_HW (PRES*PRES)    // 65536
#define RAY_START 0.1f
#define RAY_END 2.0f
#define DELTA ((RAY_END-RAY_START)/(SC-1))

// workspace layout (in floats)
#define OFF_PLANES2  ((size_t)0)                        // 6*65536*64 bf16 = 12582912 floats
#define OFF_DEPTH_C  ((size_t)12582912)                 // 393216
#define OFF_SIGMA_C  (OFF_DEPTH_C + 393216)             // 393216
#define OFF_RGB_C    (OFF_SIGMA_C + 393216)             // 12582912
#define OFF_DEPTH_F  (OFF_RGB_C + 12582912)             // 393216
#define OFF_SIGMA_F  (OFF_DEPTH_F + 393216)             // 393216
#define OFF_RGB_F    (OFF_SIGMA_F + 393216)             // 12582912
#define OFF_MINMAX   (OFF_RGB_F + 12582912)             // 2 uints (+2 pad)
#define OFF_W2T      (OFF_MINMAX + 4)                   // 33*64 floats (w2 transposed)

typedef __attribute__((ext_vector_type(2))) float f2_t;

// packed fp32 FMA: acc.{x,y} += a.{x,y} * b.{x,y}  (one VOP3P inst = 2 FMA)
__device__ __forceinline__ void pk_fma_vv(f2_t& acc, f2_t a, f2_t b) {
    asm("v_pk_fma_f32 %0, %1, %2, %0" : "+v"(acc) : "v"(a), "v"(b));
}
// variant with the (single allowed) scalar operand: b must be wave-uniform
__device__ __forceinline__ void pk_fma_vs(f2_t& acc, f2_t a, f2_t b) {
    asm("v_pk_fma_f32 %0, %1, %2, %0" : "+v"(acc) : "v"(a), "s"(b));
}
// dword of 2 packed bf16 -> f2_t {lo, hi}
__device__ __forceinline__ f2_t bfpair(unsigned int u) {
    union { unsigned int i; float f; } lo, hi;
    lo.i = u << 16;
    hi.i = u & 0xffff0000u;
    f2_t r; r.x = lo.f; r.y = hi.f;
    return r;
}

__device__ __forceinline__ float softplusf(float x) {
    return fmaxf(x, 0.f) + __logf(1.f + __expf(-fabsf(x)));
}
__device__ __forceinline__ float sigact(float o) {
    float r = __builtin_amdgcn_rcpf(1.f + __expf(-o));
    return fmaf(1.002f, r, -0.001f);
}
__device__ __forceinline__ unsigned short f2bf(float f) {
    union { float f; unsigned int u; } v; v.f = f;
    unsigned int r = v.u + 0x7fffu + ((v.u >> 16) & 1u);   // RNE
    return (unsigned short)(r >> 16);
}
__device__ __forceinline__ unsigned int pack2(float lo, float hi) {
    return (unsigned int)f2bf(lo) | ((unsigned int)f2bf(hi) << 16);
}

// ---------------------------------------------------------------------------
// Kernel 1: precompute planes2[bp][y][x][j] = bf16( sum_c planes[bp][c][y][x] * w1[c][j] )
// Single pass over c (R10 read the 100MB planes twice). Also: w2t = w2^T.
__global__ __launch_bounds__(256) void precompute2(
    const float* __restrict__ planes, const float* __restrict__ w1,
    const float* __restrict__ w2,
    unsigned short* __restrict__ planes2, float* __restrict__ w2t)
{
    if (blockIdx.x == 0 && threadIdx.x < ODIM) {
        int k = threadIdx.x;
        for (int j = 0; j < HID; ++j) w2t[k * HID + j] = w2[j * ODIM + k];
    }
    int row = blockIdx.x;
    int bp = row >> 8, y = row & 255;
    int x = threadIdx.x;
    const float* src = planes + (size_t)bp * CF * PLANE_HW + (size_t)y * PRES + x;
    unsigned short* dst = planes2 + ((size_t)bp * PLANE_HW + (size_t)y * PRES + x) * HID;
    f2_t acc[32];
    #pragma unroll
    for (int j = 0; j < 32; ++j) acc[j] = (f2_t){0.f, 0.f};
    for (int c = 0; c < CF; ++c) {
        float f = src[(size_t)c * PLANE_HW];
        f2_t fp; fp.x = f; fp.y = f;
        const f2_t* w1p = (const f2_t*)(w1 + c * HID);
        #pragma unroll
        for (int j = 0; j < 32; ++j) pk_fma_vs(acc[j], fp, w1p[j]);
    }
    #pragma unroll
    for (int q = 0; q < 8; ++q) {
        uint4 u;
        u.x = pack2(acc[q*4+0].x, acc[q*4+0].y);
        u.y = pack2(acc[q*4+1].x, acc[q*4+1].y);
        u.z = pack2(acc[q*4+2].x, acc[q*4+2].y);
        u.w = pack2(acc[q*4+3].x, acc[q*4+3].y);
        ((uint4*)dst)[q] = u;
    }
}

// ---------------------------------------------------------------------------
// Kernel 2: gather + softplus + packed 64->33 GEMM2. (unchanged from R10 —
// near its TA-throughput floor: 37.7M divergent 16B requests/dispatch)
__global__ __launch_bounds__(256, 3) void sample_mlp(
    const unsigned short* __restrict__ planes2,
    const float* __restrict__ depths_in,   // fine pass
    const float* __restrict__ noise,       // coarse pass
    float* __restrict__ depth_out,         // coarse pass
    const float* __restrict__ origins,
    const float* __restrict__ dirs,
    const float* __restrict__ b1,
    const float* __restrict__ w2t, const float* __restrict__ b2,
    float* __restrict__ sigma_out, float* __restrict__ rgb_out,
    int coarse)
{
    __shared__ __align__(8) float s_part[2][64][34];   // 17408 B

    int lane = threadIdx.x & 63;
    int wv = threadIdx.x >> 6;
    int halfu = __builtin_amdgcn_readfirstlane(wv & 1);   // SGPR: keeps weight loads scalar
    int pairu = __builtin_amdgcn_readfirstlane(wv >> 1);
    int sample = blockIdx.x * 128 + pairu * 64 + lane;
    int ray = sample / SC;
    int b = ray >> 12;

    float depth;
    if (coarse) {
        int s = sample - ray * SC;
        depth = RAY_START + (float)s * DELTA + noise[sample] * DELTA;
        if (halfu == 0) depth_out[sample] = depth;
    } else {
        depth = depths_in[sample];
    }

    float ox = origins[ray*3+0], oy = origins[ray*3+1], oz = origins[ray*3+2];
    float dx = dirs[ray*3+0],    dy = dirs[ray*3+1],    dz = dirs[ray*3+2];
    float cx = (ox + depth*dx) * 0.5f;
    float cy = (oy + depth*dy) * 0.5f;
    float cz = (oz + depth*dz) * 0.5f;

    f2_t h2[16];
    #pragma unroll
    for (int j = 0; j < 16; ++j) h2[j] = (f2_t){0.f, 0.f};

    #pragma unroll
    for (int p = 0; p < 3; ++p) {
        float gx = (p == 0) ? cx : (p == 1) ? cy : cz;
        float gy = (p == 0) ? cy : (p == 1) ? cz : cx;
        float x = fmaf(gx, 128.f, 127.5f);
        float y = fmaf(gy, 128.f, 127.5f);
        float x0f = floorf(x), y0f = floorf(y);
        float wx1 = x - x0f, wy1 = y - y0f;
        int x0 = (int)x0f, y0 = (int)y0f;
        const unsigned short* pb = planes2 + (size_t)(b*3 + p) * PLANE_HW * HID + halfu * 32;
        #pragma unroll
        for (int cyi = 0; cyi < 2; ++cyi) {
            #pragma unroll
            for (int cxi = 0; cxi < 2; ++cxi) {
                int xi = x0 + cxi, yi = y0 + cyi;
                float wgt = ((cyi ? wy1 : 1.f - wy1) * (cxi ? wx1 : 1.f - wx1)) * (1.f/3.f);
                if (xi < 0 || xi > 255 || yi < 0 || yi > 255) wgt = 0.f;
                int xc = min(max(xi, 0), 255), yc = min(max(yi, 0), 255);
                const uint4* tp = (const uint4*)(pb + (size_t)((yc << 8) + xc) * HID);
                uint4 v0 = tp[0], v1 = tp[1], v2 = tp[2], v3 = tp[3];
                f2_t wp2; wp2.x = wgt; wp2.y = wgt;
                pk_fma_vv(h2[0],  bfpair(v0.x), wp2);
                pk_fma_vv(h2[1],  bfpair(v0.y), wp2);
                pk_fma_vv(h2[2],  bfpair(v0.z), wp2);
                pk_fma_vv(h2[3],  bfpair(v0.w), wp2);
                pk_fma_vv(h2[4],  bfpair(v1.x), wp2);
                pk_fma_vv(h2[5],  bfpair(v1.y), wp2);
                pk_fma_vv(h2[6],  bfpair(v1.z), wp2);
                pk_fma_vv(h2[7],  bfpair(v1.w), wp2);
                pk_fma_vv(h2[8],  bfpair(v2.x), wp2);
                pk_fma_vv(h2[9],  bfpair(v2.y), wp2);
                pk_fma_vv(h2[10], bfpair(v2.z), wp2);
                pk_fma_vv(h2[11], bfpair(v2.w), wp2);
                pk_fma_vv(h2[12], bfpair(v3.x), wp2);
                pk_fma_vv(h2[13], bfpair(v3.y), wp2);
                pk_fma_vv(h2[14], bfpair(v3.z), wp2);
                pk_fma_vv(h2[15], bfpair(v3.w), wp2);
            }
        }
    }

    // bias + softplus for this wave's 32 channels (halfu is SGPR -> scalar b1)
    #pragma unroll
    for (int j = 0; j < 16; ++j) {
        h2[j].x = softplusf(h2[j].x + b1[halfu*32 + 2*j]);
        h2[j].y = softplusf(h2[j].y + b1[halfu*32 + 2*j + 1]);
    }

    // partial GEMM2 over own 32 channels; w2t row halves via SGPR offset.
    float o[ODIM + 1];   // pad to 34 for f2 LDS traffic
    const f2_t* wbase = (const f2_t*)(w2t + halfu * 32);
    #pragma unroll
    for (int k = 0; k < ODIM; ++k) {
        const f2_t* wp = wbase + k * (HID/2);
        f2_t acc = (f2_t){0.f, 0.f};
        #pragma unroll
        for (int j = 0; j < 16; ++j) pk_fma_vs(acc, h2[j], wp[j]);
        o[k] = acc.x + acc.y;
    }
    o[ODIM] = 0.f;

    if (halfu) {
        f2_t* dstp = (f2_t*)&s_part[pairu][lane][0];
        #pragma unroll
        for (int j = 0; j < 17; ++j) {
            f2_t v; v.x = o[2*j]; v.y = o[2*j+1];
            dstp[j] = v;
        }
    }
    __syncthreads();
    if (!halfu) {
        const f2_t* srcp = (const f2_t*)&s_part[pairu][lane][0];
        #pragma unroll
        for (int j = 0; j < 17; ++j) {
            f2_t v = srcp[j];
            o[2*j]   += v.x;
            o[2*j+1] += v.y;
        }
        #pragma unroll
        for (int k = 0; k < ODIM; ++k) o[k] += b2[k];

        sigma_out[sample] = o[0];
        float4* ro = (float4*)(rgb_out + (size_t)sample * 32);
        #pragma unroll
        for (int q = 0; q < 8; ++q) {
            float4 v;
            v.x = sigact(o[1 + q*4 + 0]);
            v.y = sigact(o[1 + q*4 + 1]);
            v.z = sigact(o[1 + q*4 + 2]);
            v.w = sigact(o[1 + q*4 + 3]);
            ro[q] = v;
        }
    }
}

// ---------------------------------------------------------------------------
// Kernel 3: importance sampling, one wave per ray; block-level minmax to
// scratch (bmin/bmax staged in rgb_f, overwritten later by the fine pass).
__global__ __launch_bounds__(256) void importance_kernel(
    const float* __restrict__ depth_c, const float* __restrict__ sigma_c,
    const float* __restrict__ noise_imp, float* __restrict__ depth_f,
    float* __restrict__ bmin, float* __restrict__ bmax)
{
    __shared__ float s_cdf[4][46];
    __shared__ float s_bins[4][47];
    __shared__ float s_red[8];
    int wave = threadIdx.x >> 6, lane = threadIdx.x & 63;
    int ray = blockIdx.x * 4 + wave;

    const float* d  = depth_c + (size_t)ray * SC;
    const float* sg = sigma_c + (size_t)ray * SC;
    float dval = (lane < SC) ? d[lane] : 0.f;
    float sval = (lane < SC) ? sg[lane] : 0.f;
    float dnext = __shfl_down(dval, 1);
    float snext = __shfl_down(sval, 1);

    float a = 0.f;
    if (lane < SC-1) {
        float dens = softplusf(0.5f * (sval + snext) - 1.f);
        a = 1.f - expf(-dens * (dnext - dval));
    }
    float f = (lane < SC-1) ? (1.f - a + 1e-10f) : 1.f;
    float incl = f;
    #pragma unroll
    for (int off = 1; off < 64; off <<= 1) {
        float t = __shfl_up(incl, off);
        if (lane >= off) incl *= t;
    }
    float T = (lane == 0) ? 1.f : __shfl_up(incl, 1);
    float w = a * T;
    float wm1 = __shfl_up(w, 1);
    float wp1 = __shfl_down(w, 1);
    float wn = 0.5f * (fmaxf(wm1, w) + fmaxf(w, wp1)) + 0.01f + 1e-5f;
    float g = (lane >= 1 && lane <= 45) ? wn : 0.f;
    float incl2 = g;
    #pragma unroll
    for (int off = 1; off < 64; off <<= 1) {
        float t = __shfl_up(incl2, off);
        if (lane >= off) incl2 += t;
    }
    float sum = __shfl(incl2, 45);
    if (lane == 0) s_cdf[wave][0] = 0.f;
    else if (lane <= 45) s_cdf[wave][lane] = incl2 / sum;
    if (lane < SC-1) s_bins[wave][lane] = 0.5f * (dval + dnext);
    __syncthreads();

    float fmn = 1e30f, fmx = -1e30f;
    if (lane < SC) {
        float u = noise_imp[(size_t)ray * SC + lane];
        int inds = 0;
        #pragma unroll
        for (int t = 0; t < 46; ++t) inds += (s_cdf[wave][t] <= u) ? 1 : 0;
        int below = max(inds - 1, 0), above = min(inds, 45);
        float cb = s_cdf[wave][below], ca = s_cdf[wave][above];
        float bb = s_bins[wave][below], ba = s_bins[wave][above];
        float den = (ca - cb < 1e-5f) ? 1.f : (ca - cb);
        float s = bb + (u - cb) / den * (ba - bb);
        depth_f[(size_t)ray * SC + lane] = s;
        fmn = s; fmx = s;
    }
    float d0 = __shfl(dval, 0), dlast = __shfl(dval, SC-1);
    fmn = fminf(fmn, d0); fmx = fmaxf(fmx, dlast);
    #pragma unroll
    for (int off = 32; off >= 1; off >>= 1) {
        fmn = fminf(fmn, __shfl_xor(fmn, off));
        fmx = fmaxf(fmx, __shfl_xor(fmx, off));
    }
    if (lane == 0) { s_red[wave] = fmn; s_red[4 + wave] = fmx; }
    __syncthreads();
    if (threadIdx.x == 0) {
        bmin[blockIdx.x] = fminf(fminf(s_red[0], s_red[1]), fminf(s_red[2], s_red[3]));
        bmax[blockIdx.x] = fmaxf(fmaxf(s_red[4], s_red[5]), fmaxf(s_red[6], s_red[7]));
    }
}

// ---------------------------------------------------------------------------
// Kernel 3b: fold 2048 per-block (min,max) pairs into minmax[0..1]. 1 block.
__global__ __launch_bounds__(1024) void reduce_minmax(
    const float* __restrict__ bmin, const float* __restrict__ bmax,
    unsigned int* __restrict__ minmax)
{
    int tid = threadIdx.x;
    float mn = fminf(bmin[tid], bmin[tid + 1024]);
    float mx = fmaxf(bmax[tid], bmax[tid + 1024]);
    #pragma unroll
    for (int off = 32; off >= 1; off >>= 1) {
        mn = fminf(mn, __shfl_xor(mn, off));
        mx = fmaxf(mx, __shfl_xor(mx, off));
    }
    __shared__ float smn[16], smx[16];
    int wv = tid >> 6;
    if ((tid & 63) == 0) { smn[wv] = mn; smx[wv] = mx; }
    __syncthreads();
    if (tid == 0) {
        float m = smn[0], M = smx[0];
        #pragma unroll
        for (int i = 1; i < 16; ++i) { m = fminf(m, smn[i]); M = fmaxf(M, smx[i]); }
        minmax[0] = __float_as_uint(m);
        minmax[1] = __float_as_uint(M);
    }
}

// ---------------------------------------------------------------------------
// Kernel 4: merge coarse+fine (stable rank sort of 96), final ray-march.
// R12: reverted to R10's known-passing serial-cumprod version (R11's scan
// rewrite caused absmax 8.7e-2; bug not localized by inspection — reverted).
__global__ __launch_bounds__(256) void final_march(
    const float* __restrict__ depth_c, const float* __restrict__ sigma_c,
    const float* __restrict__ rgb_c,
    const float* __restrict__ depth_f, const float* __restrict__ sigma_f,
    const float* __restrict__ rgb_f,
    const unsigned int* __restrict__ minmax,
    float* __restrict__ out)
{
    __shared__ float dall[4][96];
    __shared__ float sall[4][96];
    __shared__ float dsrt[4][96];
    __shared__ float ssrt[4][96];
    __shared__ int   perm[4][96];
    __shared__ float al[4][96];

    int wid = threadIdx.x >> 6, lane = threadIdx.x & 63;
    int ray = blockIdx.x * 4 + wid;

    for (int j = lane; j < 96; j += 64) {
        float dv, sv;
        if (j < 48) { dv = depth_c[(size_t)ray*48 + j]; sv = sigma_c[(size_t)ray*48 + j]; }
        else        { dv = depth_f[(size_t)ray*48 + j-48]; sv = sigma_f[(size_t)ray*48 + j-48]; }
        dall[wid][j] = dv; sall[wid][j] = sv;
    }
    __syncthreads();
    for (int j = lane; j < 96; j += 64) {
        float dj = dall[wid][j];
        int rank = 0;
        for (int k = 0; k < 96; ++k) {
            float dk = dall[wid][k];
            rank += (dk < dj || (dk == dj && k < j)) ? 1 : 0;
        }
        dsrt[wid][rank] = dj;
        ssrt[wid][rank] = sall[wid][j];
        perm[wid][rank] = j;
    }
    __syncthreads();
    for (int i = lane; i < 95; i += 64) {
        float dlt = dsrt[wid][i+1] - dsrt[wid][i];
        float dens = softplusf(0.5f * (ssrt[wid][i] + ssrt[wid][i+1]) - 1.f);
        al[wid][i] = 1.f - expf(-dens * dlt);
    }
    __syncthreads();
    if (lane == 0) {
        float T = 1.f, wsum = 0.f, dsum = 0.f;
        for (int i = 0; i < 95; ++i) {
            float a = al[wid][i];
            float wloc = a * T;
            T *= 1.f - a + 1e-10f;
            al[wid][i] = wloc;
            wsum += wloc;
            dsum += wloc * 0.5f * (dsrt[wid][i] + dsrt[wid][i+1]);
        }
        float depth = dsum / wsum;
        if (isnan(depth)) depth = INFINITY;
        float gmn = __uint_as_float(minmax[0]);
        float gmx = __uint_as_float(minmax[1]);
        depth = fminf(fmaxf(depth, gmn), gmx);
        out[262144 + ray] = depth;
        out[270336 + ray] = wsum;
        out[278528 + ray] = T;
    }
    __syncthreads();
    int k = lane & 31, half = lane >> 5;
    int i0 = half * 48, i1 = half ? 95 : 48;
    const float* rc = rgb_c + (size_t)ray * 48 * 32;
    const float* rf = rgb_f + (size_t)ray * 48 * 32;
    float acc = 0.f;
    int j0 = perm[wid][i0];
    float cur = (j0 < 48) ? rc[j0*32 + k] : rf[(j0-48)*32 + k];
    for (int i = i0; i < i1; ++i) {
        int jn = perm[wid][i+1];
        float nxt = (jn < 48) ? rc[jn*32 + k] : rf[(jn-48)*32 + k];
        acc += al[wid][i] * (cur + nxt);
        cur = nxt;
    }
    acc *= 0.5f;
    acc += __shfl_xor(acc, 32);
    if (half == 0) out[(size_t)ray * 32 + k] = acc * 2.f - 1.f;
}

// ---------------------------------------------------------------------------
extern "C" void kernel_launch(void* const* d_in, const int* in_sizes, int n_in,
                              void* d_out, int out_size, void* d_ws, size_t ws_size,
                              hipStream_t stream) {
    const float* planes      = (const float*)d_in[0];
    const float* origins     = (const float*)d_in[1];
    const float* dirs        = (const float*)d_in[2];
    const float* w1          = (const float*)d_in[3];
    const float* b1          = (const float*)d_in[4];
    const float* w2          = (const float*)d_in[5];
    const float* b2          = (const float*)d_in[6];
    const float* noise_strat = (const float*)d_in[7];
    const float* noise_imp   = (const float*)d_in[8];
    float* out = (float*)d_out;
    float* ws  = (float*)d_ws;

    unsigned short* planes2 = (unsigned short*)(ws + OFF_PLANES2);
    float* depth_c = ws + OFF_DEPTH_C;
    float* sigma_c = ws + OFF_SIGMA_C;
    float* rgb_c   = ws + OFF_RGB_C;
    float* depth_f = ws + OFF_DEPTH_F;
    float* sigma_f = ws + OFF_SIGMA_F;
    float* rgb_f   = ws + OFF_RGB_F;
    unsigned int* minmax = (unsigned int*)(ws + OFF_MINMAX);
    float* w2t = ws + OFF_W2T;
    // per-block minmax scratch: staged in rgb_f (overwritten later by fine pass)
    float* bmin = rgb_f;
    float* bmax = rgb_f + 2048;

    precompute2<<<1536, 256, 0, stream>>>(planes, w1, w2, planes2, w2t);
    sample_mlp<<<NSAMP/128, 256, 0, stream>>>(planes2, nullptr, noise_strat, depth_c,
                                              origins, dirs, b1, w2t, b2,
                                              sigma_c, rgb_c, 1);
    importance_kernel<<<NRAY/4, 256, 0, stream>>>(depth_c, sigma_c, noise_imp,
                                                  depth_f, bmin, bmax);
    reduce_minmax<<<1, 1024, 0, stream>>>(bmin, bmax, minmax);
    sample_mlp<<<NSAMP/128, 256, 0, stream>>>(planes2, depth_f, nullptr, nullptr,
                                              origins, dirs, b1, w2t, b2,
                                              sigma_f, rgb_f, 0);
    final_march<<<NRAY/4, 256, 0, stream>>>(depth_c, sigma_c, rgb_c,
                                            depth_f, sigma_f, rgb_f, minmax, out);
}